// Round 1
// baseline (520.082 us; speedup 1.0000x reference)
//
#include <hip/hip_runtime.h>
#include <math.h>

// Shapes (fixed by the reference):
#define S_DIM 256   // successor states
#define H_DIM 256
#define W_DIM 256
#define F_DIM 6
#define B_DIM 4096

// Kernel 1: build V[x][y] = sum_s softmax_s(vs)*vs, vs[s] = dot(succ[s,x,y,:], w).
// Grid: 256 blocks (one per x). Block: 1024 threads = y(256) x s-chunk(4).
// Each thread does an online-softmax over its 64 s values; chunks combined in LDS.
__global__ __launch_bounds__(1024) void build_vtable(const float* __restrict__ succ,
                                                     const float* __restrict__ w_lin,
                                                     float* __restrict__ V) {
    __shared__ float sm[1024];
    __shared__ float sl[1024];
    __shared__ float sn[1024];

    const int x   = blockIdx.x;
    const int tid = threadIdx.x;
    const int y   = tid & 255;   // cell column
    const int c   = tid >> 8;    // s-chunk 0..3

    const float w0 = w_lin[0], w1 = w_lin[1], w2 = w_lin[2],
                w3 = w_lin[3], w4 = w_lin[4], w5 = w_lin[5];

    float m = -INFINITY, l = 0.f, num = 0.f;

    // element index of succ[s0, x, y, 0]; per-s stride is one full H*W*F slice
    size_t idx = ((size_t)((c * 64) * H_DIM + x) * W_DIM + y) * F_DIM;
    const size_t stride = (size_t)H_DIM * W_DIM * F_DIM;

    #pragma unroll 4
    for (int i = 0; i < 64; ++i) {
        // 24 B per lane at 24B-aligned offset -> three 8B loads, lanes contiguous.
        const float2* p = (const float2*)(succ + idx);
        float2 a = p[0];
        float2 b = p[1];
        float2 d = p[2];
        float v = a.x*w0 + a.y*w1 + b.x*w2 + b.y*w3 + d.x*w4 + d.y*w5;

        // online softmax update (first iter: m=-inf -> exp(m-nm)=0, clean)
        float nm = fmaxf(m, v);
        float sc = __expf(m - nm);
        float e  = __expf(v - nm);
        l   = l   * sc + e;
        num = num * sc + e * v;
        m = nm;

        idx += stride;
    }

    sm[tid] = m; sl[tid] = l; sn[tid] = num;
    __syncthreads();

    if (tid < 256) {
        // combine the 4 chunk partials for cell (x, y=tid); stride-256 reads
        // are conflict-free (lanes consecutive within each access).
        float M = sm[tid];
        M = fmaxf(M, sm[256 + tid]);
        M = fmaxf(M, sm[512 + tid]);
        M = fmaxf(M, sm[768 + tid]);
        float L = 0.f, N = 0.f;
        #pragma unroll
        for (int cc = 0; cc < 4; ++cc) {
            float sc = __expf(sm[cc*256 + tid] - M);
            L += sl[cc*256 + tid] * sc;
            N += sn[cc*256 + tid] * sc;
        }
        V[x * 256 + tid] = N / L;
    }
}

// Kernel 2: per-b epilogue. phi layout (B,2,10): [feat0..5, ssx, ssy, esx, esy].
__global__ void eval_queries(const float* __restrict__ phi,
                             const float* __restrict__ w_lin,
                             const float* __restrict__ V,
                             float* __restrict__ out) {
    const int b = blockIdx.x * blockDim.x + threadIdx.x;
    if (b >= B_DIM) return;

    const float w0 = w_lin[0], w1 = w_lin[1], w2 = w_lin[2],
                w3 = w_lin[3], w4 = w_lin[4], w5 = w_lin[5];

    const float* p = phi + (size_t)b * 20;
    float der[2];
    #pragma unroll
    for (int t = 0; t < 2; ++t) {
        const float* q = p + t * 10;
        float pr = q[0]*w0 + q[1]*w1 + q[2]*w2 + q[3]*w3 + q[4]*w4 + q[5]*w5;
        int ssx = (int)q[6];
        int ssy = (int)q[7];
        int esx = (int)q[8];
        int esy = (int)q[9];
        float v_ss = V[ssx * 256 + ssy];
        float v_es = V[esx * 256 + esy];
        der[t] = pr + (v_es - v_ss);
    }
    float d = der[0] - der[1];
    out[b * 2 + 0] = 1.f / (1.f + __expf(-d));   // left_pred  = sigmoid(d)
    out[b * 2 + 1] = 1.f / (1.f + __expf(d));    // right_pred = sigmoid(-d)
}

extern "C" void kernel_launch(void* const* d_in, const int* in_sizes, int n_in,
                              void* d_out, int out_size, void* d_ws, size_t ws_size,
                              hipStream_t stream) {
    const float* phi   = (const float*)d_in[0];   // (4096, 2, 10) f32
    const float* w_lin = (const float*)d_in[1];   // (1, 6) f32
    const float* succ  = (const float*)d_in[2];   // (256, 256, 256, 6) f32
    float* out = (float*)d_out;                   // (4096, 2, 1) f32
    float* V   = (float*)d_ws;                    // 65536 f32 = 256 KB scratch

    build_vtable<<<256, 1024, 0, stream>>>(succ, w_lin, V);
    eval_queries<<<(B_DIM + 255) / 256, 256, 0, stream>>>(phi, w_lin, V, out);
}

// Round 2
// 519.174 us; speedup vs baseline: 1.0017x; 1.0017x over previous
//
#include <hip/hip_runtime.h>
#include <math.h>

#define S_DIM 256
#define H_DIM 256
#define W_DIM 256
#define F_DIM 6
#define B_DIM 4096

// Kernel 1: V[x][y] = sum_s softmax_s(vs)*vs, vs[s] = dot(succ[s,x,y,:], w).
// Grid: 256 blocks (one per x). Block: 1024 threads = 128 cell-pairs x 8 s-chunks.
// Each thread handles TWO adjacent y-cells via 3 aligned float4 loads (48 B/lane,
// 16 B/lane per instruction -> full coalescing), online-softmax over 32 s values.
__global__ __launch_bounds__(1024) void build_vtable(const float* __restrict__ succ,
                                                     const float* __restrict__ w_lin,
                                                     float* __restrict__ V) {
    __shared__ float sm[8][256];
    __shared__ float sl[8][256];
    __shared__ float sn[8][256];

    const int x   = blockIdx.x;
    const int tid = threadIdx.x;
    const int p   = tid & 127;   // cell pair -> cells y0=2p, y0+1
    const int c   = tid >> 7;    // s-chunk 0..7 (32 s each)
    const int y0  = p * 2;

    const float w0 = w_lin[0], w1 = w_lin[1], w2 = w_lin[2],
                w3 = w_lin[3], w4 = w_lin[4], w5 = w_lin[5];

    float m0 = -INFINITY, l0 = 0.f, n0 = 0.f;
    float m1 = -INFINITY, l1 = 0.f, n1 = 0.f;

    // element offset of succ[c*32, x, y0, 0]; 12 floats per thread = 3 float4s.
    // byte offset = 48*p + ... -> 16B-aligned.
    size_t elem = ((size_t)((c * 32) * H_DIM + x) * W_DIM + y0) * F_DIM;
    const float4* ptr = (const float4*)(succ + elem);
    const size_t stride4 = (size_t)H_DIM * W_DIM * F_DIM / 4;  // float4s per s-slice

    #pragma unroll 4
    for (int i = 0; i < 32; ++i) {
        float4 a = ptr[0];
        float4 b = ptr[1];
        float4 d = ptr[2];
        ptr += stride4;

        float v0 = a.x*w0 + a.y*w1 + a.z*w2 + a.w*w3 + b.x*w4 + b.y*w5;
        float v1 = b.z*w0 + b.w*w1 + d.x*w2 + d.y*w3 + d.z*w4 + d.w*w5;

        float nm0 = fmaxf(m0, v0);
        float sc0 = __expf(m0 - nm0);
        float e0  = __expf(v0 - nm0);
        l0 = l0 * sc0 + e0;
        n0 = n0 * sc0 + e0 * v0;
        m0 = nm0;

        float nm1 = fmaxf(m1, v1);
        float sc1 = __expf(m1 - nm1);
        float e1  = __expf(v1 - nm1);
        l1 = l1 * sc1 + e1;
        n1 = n1 * sc1 + e1 * v1;
        m1 = nm1;
    }

    sm[c][y0] = m0; sm[c][y0+1] = m1;
    sl[c][y0] = l0; sl[c][y0+1] = l1;
    sn[c][y0] = n0; sn[c][y0+1] = n1;
    __syncthreads();

    if (tid < 256) {
        // combine 8 chunk partials for cell (x, y=tid); lanes read consecutive
        // addresses per access -> conflict-free.
        float M = sm[0][tid];
        #pragma unroll
        for (int cc = 1; cc < 8; ++cc) M = fmaxf(M, sm[cc][tid]);
        float L = 0.f, N = 0.f;
        #pragma unroll
        for (int cc = 0; cc < 8; ++cc) {
            float sc = __expf(sm[cc][tid] - M);
            L += sl[cc][tid] * sc;
            N += sn[cc][tid] * sc;
        }
        V[x * 256 + tid] = N / L;
    }
}

// Kernel 2: per-b epilogue. phi layout (B,2,10): [feat0..5, ssx, ssy, esx, esy].
__global__ void eval_queries(const float* __restrict__ phi,
                             const float* __restrict__ w_lin,
                             const float* __restrict__ V,
                             float* __restrict__ out) {
    const int b = blockIdx.x * blockDim.x + threadIdx.x;
    if (b >= B_DIM) return;

    const float w0 = w_lin[0], w1 = w_lin[1], w2 = w_lin[2],
                w3 = w_lin[3], w4 = w_lin[4], w5 = w_lin[5];

    const float* p = phi + (size_t)b * 20;
    float der[2];
    #pragma unroll
    for (int t = 0; t < 2; ++t) {
        const float* q = p + t * 10;
        float pr = q[0]*w0 + q[1]*w1 + q[2]*w2 + q[3]*w3 + q[4]*w4 + q[5]*w5;
        int ssx = (int)q[6];
        int ssy = (int)q[7];
        int esx = (int)q[8];
        int esy = (int)q[9];
        float v_ss = V[ssx * 256 + ssy];
        float v_es = V[esx * 256 + esy];
        der[t] = pr + (v_es - v_ss);
    }
    float d = der[0] - der[1];
    out[b * 2 + 0] = 1.f / (1.f + __expf(-d));
    out[b * 2 + 1] = 1.f / (1.f + __expf(d));
}

extern "C" void kernel_launch(void* const* d_in, const int* in_sizes, int n_in,
                              void* d_out, int out_size, void* d_ws, size_t ws_size,
                              hipStream_t stream) {
    const float* phi   = (const float*)d_in[0];   // (4096, 2, 10) f32
    const float* w_lin = (const float*)d_in[1];   // (1, 6) f32
    const float* succ  = (const float*)d_in[2];   // (256, 256, 256, 6) f32
    float* out = (float*)d_out;                   // (4096, 2, 1) f32
    float* V   = (float*)d_ws;                    // 65536 f32 = 256 KB scratch

    build_vtable<<<256, 1024, 0, stream>>>(succ, w_lin, V);
    eval_queries<<<(B_DIM + 255) / 256, 256, 0, stream>>>(phi, w_lin, V, out);
}

// Round 3
// 516.282 us; speedup vs baseline: 1.0074x; 1.0056x over previous
//
#include <hip/hip_runtime.h>
#include <math.h>

#define S_DIM 256
#define H_DIM 256
#define W_DIM 256
#define F_DIM 6
#define B_DIM 4096
#define SLICE ((size_t)H_DIM * W_DIM * F_DIM)   // floats per s-slice = 393216

// ws layout: [0, 65536) f32 V table | [65536, 65536+2048 u32) needed-cell bitmap

// Kernel A: build 65536-bit mask of needed (x,y) cells from phi coords.
// Single block: zero LDS mask, scan 16384 (b,t) records, atomicOr, flush.
__global__ __launch_bounds__(1024) void build_mask(const float* __restrict__ phi,
                                                   unsigned int* __restrict__ mask) {
    __shared__ unsigned int lmask[2048];
    const int tid = threadIdx.x;
    lmask[tid] = 0u;
    lmask[tid + 1024] = 0u;
    __syncthreads();
    for (int r = tid; r < B_DIM * 2; r += 1024) {
        const float* q = phi + (size_t)r * 10;   // record (b,t), 10 floats
        float2 a = *(const float2*)(q + 6);      // ssx, ssy  (8B-aligned: offset even)
        float2 b = *(const float2*)(q + 8);      // esx, esy
        int c0 = ((int)a.x) * 256 + (int)a.y;
        int c1 = ((int)b.x) * 256 + (int)b.y;
        atomicOr(&lmask[c0 >> 5], 1u << (c0 & 31));
        atomicOr(&lmask[c1 >> 5], 1u << (c1 & 31));
    }
    __syncthreads();
    mask[tid] = lmask[tid];
    mask[tid + 1024] = lmask[tid + 1024];
}

// Kernel B: V[x][y] for NEEDED cells only. Block per x-row. Compact needed-y
// list via popcount ranks, then 8 s-chunks x 128 slots run online softmax
// over 32 s each (3x float2 gather per cell per s); 8-way LDS combine.
__global__ __launch_bounds__(1024) void build_vtable_sparse(const float* __restrict__ succ,
                                                            const float* __restrict__ w_lin,
                                                            const unsigned int* __restrict__ mask,
                                                            float* __restrict__ V) {
    __shared__ unsigned int rowmask[8];
    __shared__ int cellIdx[256];
    __shared__ int nCellsSh;
    __shared__ float sm[8][256];
    __shared__ float sl[8][256];
    __shared__ float sn[8][256];

    const int x   = blockIdx.x;
    const int tid = threadIdx.x;

    if (tid < 8) rowmask[tid] = mask[x * 8 + tid];
    __syncthreads();

    if (tid < 256) {
        const int w = tid >> 5, bit = tid & 31;
        const unsigned int mw = rowmask[w];
        int rank = 0;
        #pragma unroll
        for (int k = 0; k < 8; ++k)
            if (k < w) rank += __popc(rowmask[k]);
        rank += __popc(mw & (bit ? ((1u << bit) - 1u) : 0u));
        if ((mw >> bit) & 1u) cellIdx[rank] = tid;
        if (tid == 0) {
            int n = 0;
            #pragma unroll
            for (int k = 0; k < 8; ++k) n += __popc(rowmask[k]);
            nCellsSh = n;
        }
    }
    __syncthreads();
    const int nCells = nCellsSh;

    const float w0 = w_lin[0], w1 = w_lin[1], w2 = w_lin[2],
                w3 = w_lin[3], w4 = w_lin[4], w5 = w_lin[5];

    const int c     = tid >> 7;    // s-chunk 0..7 (32 s each)
    const int slot0 = tid & 127;

    for (int slot = slot0; slot < nCells; slot += 128) {
        const int y = cellIdx[slot];
        const float* p = succ + (size_t)(c * 32) * SLICE
                              + (size_t)(x * W_DIM + y) * F_DIM;
        float m = -INFINITY, l = 0.f, n = 0.f;
        #pragma unroll 8
        for (int i = 0; i < 32; ++i) {
            float2 a = ((const float2*)p)[0];
            float2 b = ((const float2*)p)[1];
            float2 d = ((const float2*)p)[2];
            p += SLICE;
            float v = a.x*w0 + a.y*w1 + b.x*w2 + b.y*w3 + d.x*w4 + d.y*w5;
            float nm = fmaxf(m, v);
            float sc = __expf(m - nm);
            float e  = __expf(v - nm);
            l = l * sc + e;
            n = n * sc + e * v;
            m = nm;
        }
        sm[c][slot] = m; sl[c][slot] = l; sn[c][slot] = n;
    }
    __syncthreads();

    if (tid < 256 && tid < nCells) {
        float M = sm[0][tid];
        #pragma unroll
        for (int cc = 1; cc < 8; ++cc) M = fmaxf(M, sm[cc][tid]);
        float L = 0.f, N = 0.f;
        #pragma unroll
        for (int cc = 0; cc < 8; ++cc) {
            float sc = __expf(sm[cc][tid] - M);
            L += sl[cc][tid] * sc;
            N += sn[cc][tid] * sc;
        }
        V[x * 256 + cellIdx[tid]] = N / L;
    }
}

// Kernel C: per-b epilogue. phi layout (B,2,10): [feat0..5, ssx, ssy, esx, esy].
__global__ void eval_queries(const float* __restrict__ phi,
                             const float* __restrict__ w_lin,
                             const float* __restrict__ V,
                             float* __restrict__ out) {
    const int b = blockIdx.x * blockDim.x + threadIdx.x;
    if (b >= B_DIM) return;

    const float w0 = w_lin[0], w1 = w_lin[1], w2 = w_lin[2],
                w3 = w_lin[3], w4 = w_lin[4], w5 = w_lin[5];

    const float* p = phi + (size_t)b * 20;
    float der[2];
    #pragma unroll
    for (int t = 0; t < 2; ++t) {
        const float* q = p + t * 10;
        float pr = q[0]*w0 + q[1]*w1 + q[2]*w2 + q[3]*w3 + q[4]*w4 + q[5]*w5;
        int ssx = (int)q[6];
        int ssy = (int)q[7];
        int esx = (int)q[8];
        int esy = (int)q[9];
        float v_ss = V[ssx * 256 + ssy];
        float v_es = V[esx * 256 + esy];
        der[t] = pr + (v_es - v_ss);
    }
    float d = der[0] - der[1];
    out[b * 2 + 0] = 1.f / (1.f + __expf(-d));
    out[b * 2 + 1] = 1.f / (1.f + __expf(d));
}

extern "C" void kernel_launch(void* const* d_in, const int* in_sizes, int n_in,
                              void* d_out, int out_size, void* d_ws, size_t ws_size,
                              hipStream_t stream) {
    const float* phi   = (const float*)d_in[0];   // (4096, 2, 10) f32
    const float* w_lin = (const float*)d_in[1];   // (1, 6) f32
    const float* succ  = (const float*)d_in[2];   // (256, 256, 256, 6) f32
    float* out = (float*)d_out;                   // (4096, 2, 1) f32

    float* V = (float*)d_ws;                              // 256 KB
    unsigned int* mask = (unsigned int*)(V + 65536);      // 8 KB bitmap

    build_mask<<<1, 1024, 0, stream>>>(phi, mask);
    build_vtable_sparse<<<256, 1024, 0, stream>>>(succ, w_lin, mask, V);
    eval_queries<<<(B_DIM + 255) / 256, 256, 0, stream>>>(phi, w_lin, V, out);
}